// Round 11
// baseline (625.158 us; speedup 1.0000x reference)
//
#include <hip/hip_runtime.h>
#include <cstddef>

#define HH 224
#define WW 608
#define HWSZ (HH * WW)

__device__ __forceinline__ float lrelu(float v) { return v > 0.0f ? v : 0.01f * v; }

// CondMul, output dim split across a 4-lane group (sub-lane s).
// Weight layout [i=0..31][o=0..CO-1] (wmat already offset by the gather index).
// Accumulation: i ascending per output, bias last — matches reference order.
template <int CO>
__device__ __forceinline__ void cm4(const float* wmat, const float* bvec,
                                    int s, const float (&act)[8], float (&acc)[CO / 4]) {
    constexpr int CH = CO / 4;
#pragma unroll
    for (int j = 0; j < CH; j++) acc[j] = 0.0f;
#pragma unroll
    for (int sp = 0; sp < 4; sp++) {
#pragma unroll
        for (int ii = 0; ii < 8; ii++) {
            float xi = __shfl(act[ii], sp, 4);
            const float* wr = wmat + (sp * 8 + ii) * CO + s * CH;
            if constexpr (CH == 8) {
                float4 a = *reinterpret_cast<const float4*>(wr);
                float4 b = *reinterpret_cast<const float4*>(wr + 4);
                acc[0] = fmaf(xi, a.x, acc[0]); acc[1] = fmaf(xi, a.y, acc[1]);
                acc[2] = fmaf(xi, a.z, acc[2]); acc[3] = fmaf(xi, a.w, acc[3]);
                acc[4] = fmaf(xi, b.x, acc[4]); acc[5] = fmaf(xi, b.y, acc[5]);
                acc[6] = fmaf(xi, b.z, acc[6]); acc[7] = fmaf(xi, b.w, acc[7]);
            } else {
                float4 a = *reinterpret_cast<const float4*>(wr);
                acc[0] = fmaf(xi, a.x, acc[0]); acc[1] = fmaf(xi, a.y, acc[1]);
                acc[2] = fmaf(xi, a.z, acc[2]); acc[3] = fmaf(xi, a.w, acc[3]);
            }
        }
    }
#pragma unroll
    for (int j = 0; j < CH; j++) acc[j] += bvec[s * CH + j];
}

// Pair CondMul: two pixels SHARING the same weight matrix — each float4 row
// chunk is loaded ONCE and applied to both pixels (halves delivered bytes).
// Per-pixel accumulation order identical to cm4.
template <int CO>
__device__ __forceinline__ void cm4_pair(const float* __restrict__ wmat,
                                         const float* __restrict__ bvec, int s,
                                         const float (&actA)[8], const float (&actB)[8],
                                         float (&accA)[CO / 4], float (&accB)[CO / 4]) {
    constexpr int CH = CO / 4;
#pragma unroll
    for (int j = 0; j < CH; j++) { accA[j] = 0.0f; accB[j] = 0.0f; }
#pragma unroll
    for (int sp = 0; sp < 4; sp++) {
#pragma unroll
        for (int ii = 0; ii < 8; ii++) {
            float xa = __shfl(actA[ii], sp, 4);
            float xb = __shfl(actB[ii], sp, 4);
            const float* wr = wmat + (sp * 8 + ii) * CO + s * CH;
            if constexpr (CH == 8) {
                float4 a = *reinterpret_cast<const float4*>(wr);
                float4 b = *reinterpret_cast<const float4*>(wr + 4);
                accA[0] = fmaf(xa, a.x, accA[0]); accA[1] = fmaf(xa, a.y, accA[1]);
                accA[2] = fmaf(xa, a.z, accA[2]); accA[3] = fmaf(xa, a.w, accA[3]);
                accA[4] = fmaf(xa, b.x, accA[4]); accA[5] = fmaf(xa, b.y, accA[5]);
                accA[6] = fmaf(xa, b.z, accA[6]); accA[7] = fmaf(xa, b.w, accA[7]);
                accB[0] = fmaf(xb, a.x, accB[0]); accB[1] = fmaf(xb, a.y, accB[1]);
                accB[2] = fmaf(xb, a.z, accB[2]); accB[3] = fmaf(xb, a.w, accB[3]);
                accB[4] = fmaf(xb, b.x, accB[4]); accB[5] = fmaf(xb, b.y, accB[5]);
                accB[6] = fmaf(xb, b.z, accB[6]); accB[7] = fmaf(xb, b.w, accB[7]);
            } else {
                float4 a = *reinterpret_cast<const float4*>(wr);
                accA[0] = fmaf(xa, a.x, accA[0]); accA[1] = fmaf(xa, a.y, accA[1]);
                accA[2] = fmaf(xa, a.z, accA[2]); accA[3] = fmaf(xa, a.w, accA[3]);
                accB[0] = fmaf(xb, a.x, accB[0]); accB[1] = fmaf(xb, a.y, accB[1]);
                accB[2] = fmaf(xb, a.z, accB[2]); accB[3] = fmaf(xb, a.w, accB[3]);
            }
        }
    }
#pragma unroll
    for (int j = 0; j < CH; j++) { accA[j] += bvec[s * CH + j]; accB[j] += bvec[s * CH + j]; }
}

__device__ __forceinline__ void wb_lrelu8(float (&act)[8], const float (&acc)[8]) {
#pragma unroll
    for (int j = 0; j < 8; j++) act[j] = lrelu(acc[j]);
}

// First-max argmax over 16 values distributed 4-per-lane across the 4-lane group.
__device__ __forceinline__ int argmax4(const float (&v)[4], int s) {
    float bv = v[0];
    int bi = 4 * s;
#pragma unroll
    for (int j = 1; j < 4; j++) {
        if (v[j] > bv) { bv = v[j]; bi = 4 * s + j; }
    }
#pragma unroll
    for (int m = 1; m <= 2; m <<= 1) {
        float ov = __shfl_xor(bv, m, 4);
        int oi = __shfl_xor(bi, m, 4);
        if (ov > bv || (ov == bv && oi < bi)) { bv = ov; bi = oi; }
    }
    return bi;
}

// One block per image line: 1024 threads = 256 groups of 4 lanes.
// Phases: stage1 (all px) -> sort by c1 -> stage2 (sorted pairs, shared loads)
// -> sort by c12 -> stage3 (sorted pairs) -> sort by superclass -> regressor.
extern "C" __global__ __launch_bounds__(1024, 4)
void regressor_line(const float* __restrict__ x_in,
                    const float* __restrict__ w1_0, const float* __restrict__ b1_0,
                    const float* __restrict__ w1_1, const float* __restrict__ b1_1,
                    const float* __restrict__ w1_2, const float* __restrict__ b1_2,
                    const float* __restrict__ w2_0, const float* __restrict__ b2_0,
                    const float* __restrict__ w2_1, const float* __restrict__ b2_1,
                    const float* __restrict__ w2_2, const float* __restrict__ b2_2,
                    const float* __restrict__ w3_0, const float* __restrict__ b3_0,
                    const float* __restrict__ w3_1, const float* __restrict__ b3_1,
                    const float* __restrict__ w3_2, const float* __restrict__ b3_2,
                    const float* __restrict__ wr0, const float* __restrict__ br0,
                    const float* __restrict__ wr1, const float* __restrict__ br1,
                    float* __restrict__ out) {
    const int h = blockIdx.x;
    const int tid = threadIdx.x;
    const int g = tid >> 2;          // group 0..255
    const int s = tid & 3;

    __shared__ __align__(16) float sW0[1024];
    __shared__ __align__(16) float sW1[1024];
    __shared__ __align__(16) float sW2[512];
    __shared__ int key[WW];      // per-pixel sort key of the current phase
    __shared__ int perm[WW];     // sortedpos -> pixel
    __shared__ int raw12[WW];    // unclipped inds12 per pixel
    __shared__ int sleaf[WW];    // inds123 per pixel

    if (tid < 1024) {
        int i = tid >> 5, o = tid & 31;
        sW0[tid] = w1_0[h * 1024 + o * 32 + i];
        sW1[tid] = w1_1[h * 1024 + o * 32 + i];
    }
    if (tid < 512) {
        int i = tid >> 4, o = tid & 15;
        sW2[tid] = w1_2[h * 512 + o * 32 + i];
    }
    __syncthreads();

    float act[8], actB[8], acc8[8], accB8[8], acc4[4], acc4B[4];

    // ---------------- stage 1: all 608 pixels ----------------
    for (int pos = g; pos < WW; pos += 256) {
        const int base = h * WW + pos;
#pragma unroll
        for (int ii = 0; ii < 8; ii++) act[ii] = x_in[(8 * s + ii) * HWSZ + base];
        cm4<32>(sW0, b1_0 + h * 32, s, act, acc8);
        wb_lrelu8(act, acc8);
        cm4<32>(sW1, b1_1 + h * 32, s, act, acc8);
        wb_lrelu8(act, acc8);
        cm4<16>(sW2, b1_2 + h * 16, s, act, acc4);
        const int i1 = argmax4(acc4, s);
        if (s == 0) key[pos] = i1;
    }
    __syncthreads();
    if (tid < WW) {                      // deterministic rank sort by class1
        int k = key[tid], r = 0;
        for (int j = 0; j < WW; j++) {
            int kj = key[j];
            r += (kj < k || (kj == k && j < tid)) ? 1 : 0;
        }
        perm[r] = tid;
    }
    __syncthreads();

    // ---------------- stage 2: sorted pairs, shared loads ----------------
    for (int pp = g; pp < WW / 2; pp += 256) {
        const int pxA = perm[2 * pp], pxB = perm[2 * pp + 1];
        const int i1A = key[pxA], i1B = key[pxB];
        const int baseA = h * WW + pxA, baseB = h * WW + pxB;
#pragma unroll
        for (int ii = 0; ii < 8; ii++) {
            act[ii]  = x_in[(32 + 8 * s + ii) * HWSZ + baseA];
            actB[ii] = x_in[(32 + 8 * s + ii) * HWSZ + baseB];
        }
        const size_t iA = (size_t)h * 16 + (size_t)i1A;
        const size_t iB = (size_t)h * 16 + (size_t)i1B;
        if (i1A == i1B) {
            cm4_pair<32>(w2_0 + iA * 1024, b2_0 + iA * 32, s, act, actB, acc8, accB8);
            wb_lrelu8(act, acc8); wb_lrelu8(actB, accB8);
            cm4_pair<32>(w2_1 + iA * 1024, b2_1 + iA * 32, s, act, actB, acc8, accB8);
            wb_lrelu8(act, acc8); wb_lrelu8(actB, accB8);
            cm4_pair<16>(w2_2 + iA * 512, b2_2 + iA * 16, s, act, actB, acc4, acc4B);
        } else {
            cm4<32>(w2_0 + iA * 1024, b2_0 + iA * 32, s, act, acc8);
            wb_lrelu8(act, acc8);
            cm4<32>(w2_1 + iA * 1024, b2_1 + iA * 32, s, act, acc8);
            wb_lrelu8(act, acc8);
            cm4<16>(w2_2 + iA * 512, b2_2 + iA * 16, s, act, acc4);
            cm4<32>(w2_0 + iB * 1024, b2_0 + iB * 32, s, actB, accB8);
            wb_lrelu8(actB, accB8);
            cm4<32>(w2_1 + iB * 1024, b2_1 + iB * 32, s, actB, accB8);
            wb_lrelu8(actB, accB8);
            cm4<16>(w2_2 + iB * 512, b2_2 + iB * 16, s, actB, acc4B);
        }
        const int i2A = argmax4(acc4, s);
        const int i2B = argmax4(acc4B, s);
        if (s == 0) {
            raw12[pxA] = i1A * 12 + (i2A - 2);   // unclipped
            raw12[pxB] = i1B * 12 + (i2B - 2);
        }
    }
    __syncthreads();
    if (tid < WW) key[tid] = min(max(raw12[tid], 0), 191);
    __syncthreads();
    if (tid < WW) {                      // rank sort by clipped class12
        int k = key[tid], r = 0;
        for (int j = 0; j < WW; j++) {
            int kj = key[j];
            r += (kj < k || (kj == k && j < tid)) ? 1 : 0;
        }
        perm[r] = tid;
    }
    __syncthreads();

    // ---------------- stage 3: sorted pairs, shared loads ----------------
    for (int pp = g; pp < WW / 2; pp += 256) {
        const int pxA = perm[2 * pp], pxB = perm[2 * pp + 1];
        const int cA = key[pxA], cB = key[pxB];
        const int rA = raw12[pxA], rB = raw12[pxB];
        const int baseA = h * WW + pxA, baseB = h * WW + pxB;
#pragma unroll
        for (int ii = 0; ii < 8; ii++) {
            act[ii]  = x_in[(64 + 8 * s + ii) * HWSZ + baseA];
            actB[ii] = x_in[(64 + 8 * s + ii) * HWSZ + baseB];
        }
        const size_t iA = (size_t)h * 192 + (size_t)cA;
        const size_t iB = (size_t)h * 192 + (size_t)cB;
        if (cA == cB) {
            cm4_pair<32>(w3_0 + iA * 1024, b3_0 + iA * 32, s, act, actB, acc8, accB8);
            wb_lrelu8(act, acc8); wb_lrelu8(actB, accB8);
            cm4_pair<32>(w3_1 + iA * 1024, b3_1 + iA * 32, s, act, actB, acc8, accB8);
            wb_lrelu8(act, acc8); wb_lrelu8(actB, accB8);
            cm4_pair<16>(w3_2 + iA * 512, b3_2 + iA * 16, s, act, actB, acc4, acc4B);
        } else {
            cm4<32>(w3_0 + iA * 1024, b3_0 + iA * 32, s, act, acc8);
            wb_lrelu8(act, acc8);
            cm4<32>(w3_1 + iA * 1024, b3_1 + iA * 32, s, act, acc8);
            wb_lrelu8(act, acc8);
            cm4<16>(w3_2 + iA * 512, b3_2 + iA * 16, s, act, acc4);
            cm4<32>(w3_0 + iB * 1024, b3_0 + iB * 32, s, actB, accB8);
            wb_lrelu8(actB, accB8);
            cm4<32>(w3_1 + iB * 1024, b3_1 + iB * 32, s, actB, accB8);
            wb_lrelu8(actB, accB8);
            cm4<16>(w3_2 + iB * 512, b3_2 + iB * 16, s, actB, acc4B);
        }
        const int i3A = argmax4(acc4, s);
        const int i3B = argmax4(acc4B, s);
        if (s == 0) {
            sleaf[pxA] = min(max(rA * 10 + (i3A - 3), 0), 1919);
            sleaf[pxB] = min(max(rB * 10 + (i3B - 3), 0), 1919);
        }
    }
    __syncthreads();
    if (tid < WW) key[tid] = sleaf[tid] / 5;
    __syncthreads();
    if (tid < WW) {                      // rank sort by superclass
        int k = key[tid], r = 0;
        for (int j = 0; j < WW; j++) {
            int kj = key[j];
            r += (kj < k || (kj == k && j < tid)) ? 1 : 0;
        }
        perm[r] = tid;
    }
    __syncthreads();

    // ---------------- regressor: sorted pairs ----------------
    for (int pp = g; pp < WW / 2; pp += 256) {
        const int pxA = perm[2 * pp], pxB = perm[2 * pp + 1];
        const int supA = key[pxA], supB = key[pxB];
        const int leafA = sleaf[pxA], leafB = sleaf[pxB];
        const int baseA = h * WW + pxA, baseB = h * WW + pxB;
#pragma unroll
        for (int ii = 0; ii < 8; ii++) {
            act[ii]  = x_in[(96 + 8 * s + ii) * HWSZ + baseA];
            actB[ii] = x_in[(96 + 8 * s + ii) * HWSZ + baseB];
        }
        const size_t iA = (size_t)h * 384 + (size_t)supA;
        const size_t iB = (size_t)h * 384 + (size_t)supB;
        if (supA == supB) {
            cm4_pair<32>(wr0 + iA * 1024, br0 + iA * 32, s, act, actB, acc8, accB8);
        } else {
            cm4<32>(wr0 + iA * 1024, br0 + iA * 32, s, act, acc8);
            cm4<32>(wr0 + iB * 1024, br0 + iB * 32, s, actB, accB8);
        }
        wb_lrelu8(act, acc8);
        wb_lrelu8(actB, accB8);

        const size_t irA = (size_t)h * 1920 + (size_t)leafA;
        const size_t irB = (size_t)h * 1920 + (size_t)leafB;
        const float* ra = wr1 + irA * 32 + 8 * s;
        const float* rb = wr1 + irB * 32 + 8 * s;
        float4 wa0 = *reinterpret_cast<const float4*>(ra);
        float4 wa1 = *reinterpret_cast<const float4*>(ra + 4);
        float4 wb0 = *reinterpret_cast<const float4*>(rb);
        float4 wb1 = *reinterpret_cast<const float4*>(rb + 4);
        float rpA = 0.0f, rpB = 0.0f;
        rpA = fmaf(act[0], wa0.x, rpA); rpA = fmaf(act[1], wa0.y, rpA);
        rpA = fmaf(act[2], wa0.z, rpA); rpA = fmaf(act[3], wa0.w, rpA);
        rpA = fmaf(act[4], wa1.x, rpA); rpA = fmaf(act[5], wa1.y, rpA);
        rpA = fmaf(act[6], wa1.z, rpA); rpA = fmaf(act[7], wa1.w, rpA);
        rpB = fmaf(actB[0], wb0.x, rpB); rpB = fmaf(actB[1], wb0.y, rpB);
        rpB = fmaf(actB[2], wb0.z, rpB); rpB = fmaf(actB[3], wb0.w, rpB);
        rpB = fmaf(actB[4], wb1.x, rpB); rpB = fmaf(actB[5], wb1.y, rpB);
        rpB = fmaf(actB[6], wb1.z, rpB); rpB = fmaf(actB[7], wb1.w, rpB);
        rpA += __shfl_xor(rpA, 1, 4);
        rpA += __shfl_xor(rpA, 2, 4);
        rpB += __shfl_xor(rpB, 1, 4);
        rpB += __shfl_xor(rpB, 2, 4);
        const float resA = rpA + br1[irA];
        const float resB = rpB + br1[irB];

        if (s == 0) {
            float vA = ((float)leafA + resA) * (1.0f / 1920.0f);
            out[baseA] = (vA - 0.1f) * 1.25f;
            float vB = ((float)leafB + resB) * (1.0f / 1920.0f);
            out[baseB] = (vB - 0.1f) * 1.25f;
        }
    }
}

extern "C" void kernel_launch(void* const* d_in, const int* in_sizes, int n_in,
                              void* d_out, int out_size, void* d_ws, size_t ws_size,
                              hipStream_t stream) {
    const float* p[23];
    for (int i = 0; i < 23; i++) p[i] = (const float*)d_in[i];
    regressor_line<<<dim3(HH), 1024, 0, stream>>>(
        p[0],
        p[1], p[2], p[3], p[4], p[5], p[6],
        p[7], p[8], p[9], p[10], p[11], p[12],
        p[13], p[14], p[15], p[16], p[17], p[18],
        p[19], p[20], p[21], p[22],
        (float*)d_out);
}

// Round 12
// 259.030 us; speedup vs baseline: 2.4135x; 2.4135x over previous
//
#include <hip/hip_runtime.h>
#include <cstddef>

#define HH 224
#define WW 608
#define HWSZ (HH * WW)
#define BLKPX 128

__device__ __forceinline__ float lrelu(float v) { return v > 0.0f ? v : 0.01f * v; }

// CondMul, output dim split across a 4-lane group (sub-lane s).
// Weight layout [i=0..31][o=0..CO-1] (wmat already offset by the gather index).
// Generic pointer: works for LDS (stage-1) and global weights.
// Accumulation: i ascending per output, bias last — matches reference order.
template <int CO>
__device__ __forceinline__ void cm4(const float* wmat, const float* bvec,
                                    int s, const float (&act)[8], float (&acc)[CO / 4]) {
    constexpr int CH = CO / 4;
#pragma unroll
    for (int j = 0; j < CH; j++) acc[j] = 0.0f;
#pragma unroll
    for (int sp = 0; sp < 4; sp++) {
#pragma unroll
        for (int ii = 0; ii < 8; ii++) {
            float xi = __shfl(act[ii], sp, 4);
            const float* wr = wmat + (sp * 8 + ii) * CO + s * CH;
            if constexpr (CH == 8) {
                float4 a = *reinterpret_cast<const float4*>(wr);
                float4 b = *reinterpret_cast<const float4*>(wr + 4);
                acc[0] = fmaf(xi, a.x, acc[0]); acc[1] = fmaf(xi, a.y, acc[1]);
                acc[2] = fmaf(xi, a.z, acc[2]); acc[3] = fmaf(xi, a.w, acc[3]);
                acc[4] = fmaf(xi, b.x, acc[4]); acc[5] = fmaf(xi, b.y, acc[5]);
                acc[6] = fmaf(xi, b.z, acc[6]); acc[7] = fmaf(xi, b.w, acc[7]);
            } else {
                float4 a = *reinterpret_cast<const float4*>(wr);
                acc[0] = fmaf(xi, a.x, acc[0]); acc[1] = fmaf(xi, a.y, acc[1]);
                acc[2] = fmaf(xi, a.z, acc[2]); acc[3] = fmaf(xi, a.w, acc[3]);
            }
        }
    }
#pragma unroll
    for (int j = 0; j < CH; j++) acc[j] += bvec[s * CH + j];
}

// Pair CondMul: two pixels SHARING one weight matrix — each float4 row chunk
// is loaded ONCE and applied to both pixels (halves delivered weight bytes).
// Per-pixel fmaf order identical to cm4.
template <int CO>
__device__ __forceinline__ void cm4_pair(const float* __restrict__ wmat,
                                         const float* __restrict__ bvec, int s,
                                         const float (&actA)[8], const float (&actB)[8],
                                         float (&accA)[CO / 4], float (&accB)[CO / 4]) {
    constexpr int CH = CO / 4;
#pragma unroll
    for (int j = 0; j < CH; j++) { accA[j] = 0.0f; accB[j] = 0.0f; }
#pragma unroll
    for (int sp = 0; sp < 4; sp++) {
#pragma unroll
        for (int ii = 0; ii < 8; ii++) {
            float xa = __shfl(actA[ii], sp, 4);
            float xb = __shfl(actB[ii], sp, 4);
            const float* wr = wmat + (sp * 8 + ii) * CO + s * CH;
            if constexpr (CH == 8) {
                float4 a = *reinterpret_cast<const float4*>(wr);
                float4 b = *reinterpret_cast<const float4*>(wr + 4);
                accA[0] = fmaf(xa, a.x, accA[0]); accA[1] = fmaf(xa, a.y, accA[1]);
                accA[2] = fmaf(xa, a.z, accA[2]); accA[3] = fmaf(xa, a.w, accA[3]);
                accA[4] = fmaf(xa, b.x, accA[4]); accA[5] = fmaf(xa, b.y, accA[5]);
                accA[6] = fmaf(xa, b.z, accA[6]); accA[7] = fmaf(xa, b.w, accA[7]);
                accB[0] = fmaf(xb, a.x, accB[0]); accB[1] = fmaf(xb, a.y, accB[1]);
                accB[2] = fmaf(xb, a.z, accB[2]); accB[3] = fmaf(xb, a.w, accB[3]);
                accB[4] = fmaf(xb, b.x, accB[4]); accB[5] = fmaf(xb, b.y, accB[5]);
                accB[6] = fmaf(xb, b.z, accB[6]); accB[7] = fmaf(xb, b.w, accB[7]);
            } else {
                float4 a = *reinterpret_cast<const float4*>(wr);
                accA[0] = fmaf(xa, a.x, accA[0]); accA[1] = fmaf(xa, a.y, accA[1]);
                accA[2] = fmaf(xa, a.z, accA[2]); accA[3] = fmaf(xa, a.w, accA[3]);
                accB[0] = fmaf(xb, a.x, accB[0]); accB[1] = fmaf(xb, a.y, accB[1]);
                accB[2] = fmaf(xb, a.z, accB[2]); accB[3] = fmaf(xb, a.w, accB[3]);
            }
        }
    }
#pragma unroll
    for (int j = 0; j < CH; j++) { accA[j] += bvec[s * CH + j]; accB[j] += bvec[s * CH + j]; }
}

__device__ __forceinline__ void wb_lrelu8(float (&act)[8], const float (&acc)[8]) {
#pragma unroll
    for (int j = 0; j < 8; j++) act[j] = lrelu(acc[j]);
}

// First-max argmax over 16 values distributed 4-per-lane across the 4-lane group.
__device__ __forceinline__ int argmax4(const float (&v)[4], int s) {
    float bv = v[0];
    int bi = 4 * s;
#pragma unroll
    for (int j = 1; j < 4; j++) {
        if (v[j] > bv) { bv = v[j]; bi = 4 * s + j; }
    }
#pragma unroll
    for (int m = 1; m <= 2; m <<= 1) {
        float ov = __shfl_xor(bv, m, 4);
        int oi = __shfl_xor(bi, m, 4);
        if (ov > bv || (ov == bv && oi < bi)) { bv = ov; bi = oi; }
    }
    return bi;
}

extern "C" __global__ __launch_bounds__(256, 3)
void regressor_fused(const float* __restrict__ x_in,
                     const float* __restrict__ w1_0, const float* __restrict__ b1_0,
                     const float* __restrict__ w1_1, const float* __restrict__ b1_1,
                     const float* __restrict__ w1_2, const float* __restrict__ b1_2,
                     const float* __restrict__ w2_0, const float* __restrict__ b2_0,
                     const float* __restrict__ w2_1, const float* __restrict__ b2_1,
                     const float* __restrict__ w2_2, const float* __restrict__ b2_2,
                     const float* __restrict__ w3_0, const float* __restrict__ b3_0,
                     const float* __restrict__ w3_1, const float* __restrict__ b3_1,
                     const float* __restrict__ w3_2, const float* __restrict__ b3_2,
                     const float* __restrict__ wr0, const float* __restrict__ br0,
                     const float* __restrict__ wr1, const float* __restrict__ br1,
                     float* __restrict__ out) {
    const int h = blockIdx.y;
    const int tid = threadIdx.x;
    const int g = tid >> 2;          // group 0..63 (4 lanes each)
    const int s = tid & 3;
    const int base0 = blockIdx.x * BLKPX;

    __shared__ __align__(16) float sW0[1024];
    __shared__ __align__(16) float sW1[1024];
    __shared__ __align__(16) float sW2[512];
    __shared__ __align__(16) float xbuf[32][BLKPX + 1];  // coalesced stage, permuted read
    __shared__ int key[BLKPX];    // per-slot sort key of the current phase
    __shared__ int perm[BLKPX];   // sortedpos -> slot
    __shared__ int raw12[BLKPX];  // unclipped inds12 per slot
    __shared__ int lf[BLKPX];     // inds123 per slot

    for (int tt = tid; tt < 1024; tt += 256) {
        int i = tt >> 5, o = tt & 31;
        sW0[tt] = w1_0[h * 1024 + o * 32 + i];
        sW1[tt] = w1_1[h * 1024 + o * 32 + i];
    }
    for (int tt = tid; tt < 512; tt += 256) {
        int i = tt >> 4, o = tt & 15;
        sW2[tt] = w1_2[h * 512 + o * 32 + i];
    }
    __syncthreads();

    float act[8], actB[8], acc8[8], accB8[8], acc4[4], acc4B[4];

    // ---------------- stage 1: two slots per group, per-line MLP -> c1 ----------------
#pragma unroll
    for (int rep = 0; rep < 2; rep++) {
        const int q = g + 64 * rep;
        const int bs = h * WW + min(base0 + q, WW - 1);   // tail slots: duplicate px
#pragma unroll
        for (int ii = 0; ii < 8; ii++) act[ii] = x_in[(8 * s + ii) * HWSZ + bs];
        cm4<32>(sW0, b1_0 + h * 32, s, act, acc8);
        wb_lrelu8(act, acc8);
        cm4<32>(sW1, b1_1 + h * 32, s, act, acc8);
        wb_lrelu8(act, acc8);
        cm4<16>(sW2, b1_2 + h * 16, s, act, acc4);
        const int i1 = argmax4(acc4, s);
        if (s == 0) key[q] = i1;
    }
    __syncthreads();
    if (tid < BLKPX) {                   // deterministic rank sort by class1
        int k = key[tid], r = 0;
        for (int j = 0; j < BLKPX; j++) {
            int kj = key[j];
            r += (kj < k || (kj == k && j < tid)) ? 1 : 0;
        }
        perm[r] = tid;
    }
    __syncthreads();

    // ---------------- stage 2: sorted pairs, shared loads ----------------
    for (int t = tid; t < 32 * BLKPX; t += 256) {        // coalesced act staging
        int ch = t >> 7, q = t & (BLKPX - 1);
        xbuf[ch][q] = x_in[(32 + ch) * HWSZ + h * WW + min(base0 + q, WW - 1)];
    }
    __syncthreads();
    {
        const int qA = perm[2 * g], qB = perm[2 * g + 1];
        const int i1A = key[qA], i1B = key[qB];
#pragma unroll
        for (int ii = 0; ii < 8; ii++) {
            act[ii]  = xbuf[8 * s + ii][qA];
            actB[ii] = xbuf[8 * s + ii][qB];
        }
        const size_t iA = (size_t)h * 16 + (size_t)i1A;
        const size_t iB = (size_t)h * 16 + (size_t)i1B;
        if (i1A == i1B) {
            cm4_pair<32>(w2_0 + iA * 1024, b2_0 + iA * 32, s, act, actB, acc8, accB8);
            wb_lrelu8(act, acc8); wb_lrelu8(actB, accB8);
            cm4_pair<32>(w2_1 + iA * 1024, b2_1 + iA * 32, s, act, actB, acc8, accB8);
            wb_lrelu8(act, acc8); wb_lrelu8(actB, accB8);
            cm4_pair<16>(w2_2 + iA * 512, b2_2 + iA * 16, s, act, actB, acc4, acc4B);
        } else {
            cm4<32>(w2_0 + iA * 1024, b2_0 + iA * 32, s, act, acc8);
            wb_lrelu8(act, acc8);
            cm4<32>(w2_1 + iA * 1024, b2_1 + iA * 32, s, act, acc8);
            wb_lrelu8(act, acc8);
            cm4<16>(w2_2 + iA * 512, b2_2 + iA * 16, s, act, acc4);
            cm4<32>(w2_0 + iB * 1024, b2_0 + iB * 32, s, actB, accB8);
            wb_lrelu8(actB, accB8);
            cm4<32>(w2_1 + iB * 1024, b2_1 + iB * 32, s, actB, accB8);
            wb_lrelu8(actB, accB8);
            cm4<16>(w2_2 + iB * 512, b2_2 + iB * 16, s, actB, acc4B);
        }
        const int i2A = argmax4(acc4, s);
        const int i2B = argmax4(acc4B, s);
        if (s == 0) {
            raw12[qA] = i1A * 12 + (i2A - 2);   // unclipped
            raw12[qB] = i1B * 12 + (i2B - 2);
        }
    }
    __syncthreads();
    if (tid < BLKPX) key[tid] = min(max(raw12[tid], 0), 191);
    __syncthreads();
    if (tid < BLKPX) {                   // rank sort by clipped class12
        int k = key[tid], r = 0;
        for (int j = 0; j < BLKPX; j++) {
            int kj = key[j];
            r += (kj < k || (kj == k && j < tid)) ? 1 : 0;
        }
        perm[r] = tid;
    }
    __syncthreads();

    // ---------------- stage 3: sorted pairs, shared loads ----------------
    for (int t = tid; t < 32 * BLKPX; t += 256) {
        int ch = t >> 7, q = t & (BLKPX - 1);
        xbuf[ch][q] = x_in[(64 + ch) * HWSZ + h * WW + min(base0 + q, WW - 1)];
    }
    __syncthreads();
    {
        const int qA = perm[2 * g], qB = perm[2 * g + 1];
        const int cA = key[qA], cB = key[qB];
        const int rA = raw12[qA], rB = raw12[qB];
#pragma unroll
        for (int ii = 0; ii < 8; ii++) {
            act[ii]  = xbuf[8 * s + ii][qA];
            actB[ii] = xbuf[8 * s + ii][qB];
        }
        const size_t iA = (size_t)h * 192 + (size_t)cA;
        const size_t iB = (size_t)h * 192 + (size_t)cB;
        if (cA == cB) {
            cm4_pair<32>(w3_0 + iA * 1024, b3_0 + iA * 32, s, act, actB, acc8, accB8);
            wb_lrelu8(act, acc8); wb_lrelu8(actB, accB8);
            cm4_pair<32>(w3_1 + iA * 1024, b3_1 + iA * 32, s, act, actB, acc8, accB8);
            wb_lrelu8(act, acc8); wb_lrelu8(actB, accB8);
            cm4_pair<16>(w3_2 + iA * 512, b3_2 + iA * 16, s, act, actB, acc4, acc4B);
        } else {
            cm4<32>(w3_0 + iA * 1024, b3_0 + iA * 32, s, act, acc8);
            wb_lrelu8(act, acc8);
            cm4<32>(w3_1 + iA * 1024, b3_1 + iA * 32, s, act, acc8);
            wb_lrelu8(act, acc8);
            cm4<16>(w3_2 + iA * 512, b3_2 + iA * 16, s, act, acc4);
            cm4<32>(w3_0 + iB * 1024, b3_0 + iB * 32, s, actB, accB8);
            wb_lrelu8(actB, accB8);
            cm4<32>(w3_1 + iB * 1024, b3_1 + iB * 32, s, actB, accB8);
            wb_lrelu8(actB, accB8);
            cm4<16>(w3_2 + iB * 512, b3_2 + iB * 16, s, actB, acc4B);
        }
        const int i3A = argmax4(acc4, s);
        const int i3B = argmax4(acc4B, s);
        if (s == 0) {
            lf[qA] = min(max(rA * 10 + (i3A - 3), 0), 1919);
            lf[qB] = min(max(rB * 10 + (i3B - 3), 0), 1919);
        }
    }
    __syncthreads();
    if (tid < BLKPX) key[tid] = lf[tid] / 5;
    __syncthreads();
    if (tid < BLKPX) {                   // rank sort by superclass
        int k = key[tid], r = 0;
        for (int j = 0; j < BLKPX; j++) {
            int kj = key[j];
            r += (kj < k || (kj == k && j < tid)) ? 1 : 0;
        }
        perm[r] = tid;
    }
    __syncthreads();

    // ---------------- regressor: sorted pairs ----------------
    for (int t = tid; t < 32 * BLKPX; t += 256) {
        int ch = t >> 7, q = t & (BLKPX - 1);
        xbuf[ch][q] = x_in[(96 + ch) * HWSZ + h * WW + min(base0 + q, WW - 1)];
    }
    __syncthreads();
    {
        const int qA = perm[2 * g], qB = perm[2 * g + 1];
        const int supA = key[qA], supB = key[qB];
        const int leafA = lf[qA], leafB = lf[qB];
#pragma unroll
        for (int ii = 0; ii < 8; ii++) {
            act[ii]  = xbuf[8 * s + ii][qA];
            actB[ii] = xbuf[8 * s + ii][qB];
        }
        const size_t iA = (size_t)h * 384 + (size_t)supA;
        const size_t iB = (size_t)h * 384 + (size_t)supB;
        if (supA == supB) {
            cm4_pair<32>(wr0 + iA * 1024, br0 + iA * 32, s, act, actB, acc8, accB8);
        } else {
            cm4<32>(wr0 + iA * 1024, br0 + iA * 32, s, act, acc8);
            cm4<32>(wr0 + iB * 1024, br0 + iB * 32, s, actB, accB8);
        }
        wb_lrelu8(act, acc8);
        wb_lrelu8(actB, accB8);

        const size_t irA = (size_t)h * 1920 + (size_t)leafA;
        const size_t irB = (size_t)h * 1920 + (size_t)leafB;
        const float* ra = wr1 + irA * 32 + 8 * s;
        const float* rb = wr1 + irB * 32 + 8 * s;
        float4 wa0 = *reinterpret_cast<const float4*>(ra);
        float4 wa1 = *reinterpret_cast<const float4*>(ra + 4);
        float4 wb0 = *reinterpret_cast<const float4*>(rb);
        float4 wb1 = *reinterpret_cast<const float4*>(rb + 4);
        float rpA = 0.0f, rpB = 0.0f;
        rpA = fmaf(act[0], wa0.x, rpA); rpA = fmaf(act[1], wa0.y, rpA);
        rpA = fmaf(act[2], wa0.z, rpA); rpA = fmaf(act[3], wa0.w, rpA);
        rpA = fmaf(act[4], wa1.x, rpA); rpA = fmaf(act[5], wa1.y, rpA);
        rpA = fmaf(act[6], wa1.z, rpA); rpA = fmaf(act[7], wa1.w, rpA);
        rpB = fmaf(actB[0], wb0.x, rpB); rpB = fmaf(actB[1], wb0.y, rpB);
        rpB = fmaf(actB[2], wb0.z, rpB); rpB = fmaf(actB[3], wb0.w, rpB);
        rpB = fmaf(actB[4], wb1.x, rpB); rpB = fmaf(actB[5], wb1.y, rpB);
        rpB = fmaf(actB[6], wb1.z, rpB); rpB = fmaf(actB[7], wb1.w, rpB);
        rpA += __shfl_xor(rpA, 1, 4);
        rpA += __shfl_xor(rpA, 2, 4);
        rpB += __shfl_xor(rpB, 1, 4);
        rpB += __shfl_xor(rpB, 2, 4);
        const float resA = rpA + br1[irA];
        const float resB = rpB + br1[irB];

        if (s == 0) {
            if (base0 + qA < WW) {
                float vA = ((float)leafA + resA) * (1.0f / 1920.0f);
                out[h * WW + base0 + qA] = (vA - 0.1f) * 1.25f;
            }
            if (base0 + qB < WW) {
                float vB = ((float)leafB + resB) * (1.0f / 1920.0f);
                out[h * WW + base0 + qB] = (vB - 0.1f) * 1.25f;
            }
        }
    }
}

extern "C" void kernel_launch(void* const* d_in, const int* in_sizes, int n_in,
                              void* d_out, int out_size, void* d_ws, size_t ws_size,
                              hipStream_t stream) {
    const float* p[23];
    for (int i = 0; i < 23; i++) p[i] = (const float*)d_in[i];
    dim3 grid(5, HH);   // 128 pixels per block, pairs share weight loads
    regressor_fused<<<grid, 256, 0, stream>>>(
        p[0],
        p[1], p[2], p[3], p[4], p[5], p[6],
        p[7], p[8], p[9], p[10], p[11], p[12],
        p[13], p[14], p[15], p[16], p[17], p[18],
        p[19], p[20], p[21], p[22],
        (float*)d_out);
}

// Round 13
// 186.330 us; speedup vs baseline: 3.3551x; 1.3902x over previous
//
#include <hip/hip_runtime.h>
#include <cstddef>

#define HH 224
#define WW 608
#define HWSZ (HH * WW)

__device__ __forceinline__ float lrelu(float v) { return v > 0.0f ? v : 0.01f * v; }

// CondMul, output dim split across a 4-lane group (sub-lane s).
// Weight layout [i=0..31][o=0..CO-1] (wmat already offset by the gather index).
// Generic pointer: LDS slab or global. Accumulation: i ascending per output,
// bias last — matches reference order exactly.
template <int CO>
__device__ __forceinline__ void cm4(const float* wmat, const float* bvec,
                                    int s, const float (&act)[8], float (&acc)[CO / 4]) {
    constexpr int CH = CO / 4;
#pragma unroll
    for (int j = 0; j < CH; j++) acc[j] = 0.0f;
#pragma unroll
    for (int sp = 0; sp < 4; sp++) {
#pragma unroll
        for (int ii = 0; ii < 8; ii++) {
            float xi = __shfl(act[ii], sp, 4);
            const float* wr = wmat + (sp * 8 + ii) * CO + s * CH;
            if constexpr (CH == 8) {
                float4 a = *reinterpret_cast<const float4*>(wr);
                float4 b = *reinterpret_cast<const float4*>(wr + 4);
                acc[0] = fmaf(xi, a.x, acc[0]); acc[1] = fmaf(xi, a.y, acc[1]);
                acc[2] = fmaf(xi, a.z, acc[2]); acc[3] = fmaf(xi, a.w, acc[3]);
                acc[4] = fmaf(xi, b.x, acc[4]); acc[5] = fmaf(xi, b.y, acc[5]);
                acc[6] = fmaf(xi, b.z, acc[6]); acc[7] = fmaf(xi, b.w, acc[7]);
            } else {
                float4 a = *reinterpret_cast<const float4*>(wr);
                acc[0] = fmaf(xi, a.x, acc[0]); acc[1] = fmaf(xi, a.y, acc[1]);
                acc[2] = fmaf(xi, a.z, acc[2]); acc[3] = fmaf(xi, a.w, acc[3]);
            }
        }
    }
#pragma unroll
    for (int j = 0; j < CH; j++) acc[j] += bvec[s * CH + j];
}

__device__ __forceinline__ void wb_lrelu8(float (&act)[8], const float (&acc)[8]) {
#pragma unroll
    for (int j = 0; j < 8; j++) act[j] = lrelu(acc[j]);
}

// First-max argmax over 16 values distributed 4-per-lane across the 4-lane group.
__device__ __forceinline__ int argmax4(const float (&v)[4], int s) {
    float bv = v[0];
    int bi = 4 * s;
#pragma unroll
    for (int j = 1; j < 4; j++) {
        if (v[j] > bv) { bv = v[j]; bi = 4 * s + j; }
    }
#pragma unroll
    for (int m = 1; m <= 2; m <<= 1) {
        float ov = __shfl_xor(bv, m, 4);
        int oi = __shfl_xor(bi, m, 4);
        if (ov > bv || (ov == bv && oi < bi)) { bv = ov; bi = oi; }
    }
    return bi;
}

// Stage NF floats (16B-aligned) into this wave's private LDS slab.
// Wave-private: no barrier needed (proven in R9); compiler inserts waitcnts.
template <int NF>
__device__ __forceinline__ void stage_mat(float* ws, const float* __restrict__ src, int lane) {
    const float4* s4 = reinterpret_cast<const float4*>(src);
    float4* w4 = reinterpret_cast<float4*>(ws);
#pragma unroll
    for (int t = 0; t < NF / 4 / 64; t++) w4[t * 64 + lane] = s4[t * 64 + lane];
}

extern "C" __global__ __launch_bounds__(256, 4)
void regressor_fused(const float* __restrict__ x_in,
                     const float* __restrict__ w1_0, const float* __restrict__ b1_0,
                     const float* __restrict__ w1_1, const float* __restrict__ b1_1,
                     const float* __restrict__ w1_2, const float* __restrict__ b1_2,
                     const float* __restrict__ w2_0, const float* __restrict__ b2_0,
                     const float* __restrict__ w2_1, const float* __restrict__ b2_1,
                     const float* __restrict__ w2_2, const float* __restrict__ b2_2,
                     const float* __restrict__ w3_0, const float* __restrict__ b3_0,
                     const float* __restrict__ w3_1, const float* __restrict__ b3_1,
                     const float* __restrict__ w3_2, const float* __restrict__ b3_2,
                     const float* __restrict__ wr0, const float* __restrict__ br0,
                     const float* __restrict__ wr1, const float* __restrict__ br1,
                     float* __restrict__ out) {
    const int h = blockIdx.y;
    const int tid = threadIdx.x;
    const int p = tid >> 2;          // slot within block (0..63)
    const int s = tid & 3;           // output-chunk sub-lane (0..3)
    const int lane = tid & 63;
    const int w = blockIdx.x * 64 + p;
    const int wc = (w < WW) ? w : (WW - 1);   // tail slots: duplicate pixel
    const int base = h * WW + wc;

    __shared__ __align__(16) float sW0[1024];
    __shared__ __align__(16) float sW1[1024];
    __shared__ __align__(16) float sW2[512];
    __shared__ __align__(16) float sUni[4][1024];   // wave-private slabs
    __shared__ __align__(16) float xbuf[32][65];    // coalesced stage, permuted read
    __shared__ int skey[64];     // per-slot sort key of the current phase
    __shared__ int sperm[64];    // sortedpos -> slot
    __shared__ int sraw[64];     // unclipped inds12 per slot
    __shared__ int sraw2[64];    // inds123 per slot
    float* ws = sUni[tid >> 6];

    for (int tt = tid; tt < 1024; tt += 256) {
        int i = tt >> 5, o = tt & 31;
        sW0[tt] = w1_0[h * 1024 + o * 32 + i];
        sW1[tt] = w1_1[h * 1024 + o * 32 + i];
    }
    for (int tt = tid; tt < 512; tt += 256) {
        int i = tt >> 4, o = tt & 15;
        sW2[tt] = w1_2[h * 512 + o * 32 + i];
    }
    __syncthreads();

    float act[8], a0[8], acc8[8], acc4[4];

    // ---------------- stage 1: per-line MLP on own slot -> class1 ----------------
#pragma unroll
    for (int ii = 0; ii < 8; ii++) act[ii] = x_in[(8 * s + ii) * HWSZ + base];
    cm4<32>(sW0, b1_0 + h * 32, s, act, acc8);
    wb_lrelu8(act, acc8);
    cm4<32>(sW1, b1_1 + h * 32, s, act, acc8);
    wb_lrelu8(act, acc8);
    cm4<16>(sW2, b1_2 + h * 16, s, act, acc4);
    const int i1 = argmax4(acc4, s);
    if (s == 0) skey[p] = i1;

    // stage acts for stage-2 (coalesced, own slot)
#pragma unroll
    for (int ii = 0; ii < 8; ii++)
        xbuf[8 * s + ii][p] = x_in[(32 + 8 * s + ii) * HWSZ + base];
    __syncthreads();
    if (tid < 64) {                      // deterministic rank sort by class1
        int k = skey[tid], r = 0;
        for (int j = 0; j < 64; j++) {
            int kj = skey[j];
            r += (kj < k || (kj == k && j < tid)) ? 1 : 0;
        }
        sperm[r] = tid;
    }
    __syncthreads();

    // ---------------- stage 2: waterfall over wave's distinct classes ----------------
    {
        const int q = sperm[p];          // sorted slot this group processes
        const int mycls = skey[q];
#pragma unroll
        for (int ii = 0; ii < 8; ii++) act[ii] = xbuf[8 * s + ii][q];
        bool done = false;
        for (;;) {
            unsigned long long m = __ballot(!done);
            if (!m) break;
            const int srcl = __ffsll(m) - 1;
            const int c = __shfl(mycls, srcl);
            const size_t u = (size_t)h * 16 + (size_t)c;
            stage_mat<1024>(ws, w2_0 + u * 1024, lane);
#pragma unroll
            for (int ii = 0; ii < 8; ii++) a0[ii] = act[ii];
            cm4<32>(ws, b2_0 + u * 32, s, a0, acc8);
            wb_lrelu8(a0, acc8);
            stage_mat<1024>(ws, w2_1 + u * 1024, lane);
            cm4<32>(ws, b2_1 + u * 32, s, a0, acc8);
            wb_lrelu8(a0, acc8);
            stage_mat<512>(ws, w2_2 + u * 512, lane);
            cm4<16>(ws, b2_2 + u * 16, s, a0, acc4);
            const int i2 = argmax4(acc4, s);
            if (mycls == c) {
                if (s == 0) sraw[q] = c * 12 + (i2 - 2);   // unclipped inds12
                done = true;
            }
        }
    }
    __syncthreads();

    // stage acts for stage-3; keys from clipped inds12
#pragma unroll
    for (int ii = 0; ii < 8; ii++)
        xbuf[8 * s + ii][p] = x_in[(64 + 8 * s + ii) * HWSZ + base];
    if (tid < 64) skey[tid] = min(max(sraw[tid], 0), 191);
    __syncthreads();
    if (tid < 64) {
        int k = skey[tid], r = 0;
        for (int j = 0; j < 64; j++) {
            int kj = skey[j];
            r += (kj < k || (kj == k && j < tid)) ? 1 : 0;
        }
        sperm[r] = tid;
    }
    __syncthreads();

    // ---------------- stage 3: waterfall ----------------
    {
        const int q = sperm[p];
        const int mycls = skey[q];       // clipped c12
        const int r12 = sraw[q];         // unclipped
#pragma unroll
        for (int ii = 0; ii < 8; ii++) act[ii] = xbuf[8 * s + ii][q];
        bool done = false;
        for (;;) {
            unsigned long long m = __ballot(!done);
            if (!m) break;
            const int srcl = __ffsll(m) - 1;
            const int c = __shfl(mycls, srcl);
            const size_t u = (size_t)h * 192 + (size_t)c;
            stage_mat<1024>(ws, w3_0 + u * 1024, lane);
#pragma unroll
            for (int ii = 0; ii < 8; ii++) a0[ii] = act[ii];
            cm4<32>(ws, b3_0 + u * 32, s, a0, acc8);
            wb_lrelu8(a0, acc8);
            stage_mat<1024>(ws, w3_1 + u * 1024, lane);
            cm4<32>(ws, b3_1 + u * 32, s, a0, acc8);
            wb_lrelu8(a0, acc8);
            stage_mat<512>(ws, w3_2 + u * 512, lane);
            cm4<16>(ws, b3_2 + u * 16, s, a0, acc4);
            const int i3 = argmax4(acc4, s);
            if (mycls == c) {
                if (s == 0) sraw2[q] = min(max(r12 * 10 + (i3 - 3), 0), 1919);
                done = true;
            }
        }
    }
    __syncthreads();

    // stage acts for regressor; keys = superclass
#pragma unroll
    for (int ii = 0; ii < 8; ii++)
        xbuf[8 * s + ii][p] = x_in[(96 + 8 * s + ii) * HWSZ + base];
    if (tid < 64) skey[tid] = sraw2[tid] / 5;
    __syncthreads();
    if (tid < 64) {
        int k = skey[tid], r = 0;
        for (int j = 0; j < 64; j++) {
            int kj = skey[j];
            r += (kj < k || (kj == k && j < tid)) ? 1 : 0;
        }
        sperm[r] = tid;
    }
    __syncthreads();

    // ---------------- regressor: wr0 waterfall + per-leaf wr1 ----------------
    {
        const int q = sperm[p];
        const int leaf = sraw2[q];
        const int sup = skey[q];
#pragma unroll
        for (int ii = 0; ii < 8; ii++) act[ii] = xbuf[8 * s + ii][q];
        float res8[8];
        bool done = false;
        for (;;) {
            unsigned long long m = __ballot(!done);
            if (!m) break;
            const int srcl = __ffsll(m) - 1;
            const int c = __shfl(sup, srcl);
            const size_t u = (size_t)h * 384 + (size_t)c;
            stage_mat<1024>(ws, wr0 + u * 1024, lane);
#pragma unroll
            for (int ii = 0; ii < 8; ii++) a0[ii] = act[ii];
            cm4<32>(ws, br0 + u * 32, s, a0, acc8);
            if (sup == c) {
#pragma unroll
                for (int ii = 0; ii < 8; ii++) res8[ii] = acc8[ii];
                done = true;
            }
        }
        wb_lrelu8(a0, res8);   // a0 := lrelu(res8) — per-pixel hidden activations

        const size_t idxr = (size_t)h * 1920 + (size_t)leaf;
        const float* wr1r = wr1 + idxr * 32 + 8 * s;
        float4 wa = *reinterpret_cast<const float4*>(wr1r);
        float4 wb = *reinterpret_cast<const float4*>(wr1r + 4);
        float rpart = 0.0f;
        rpart = fmaf(a0[0], wa.x, rpart); rpart = fmaf(a0[1], wa.y, rpart);
        rpart = fmaf(a0[2], wa.z, rpart); rpart = fmaf(a0[3], wa.w, rpart);
        rpart = fmaf(a0[4], wb.x, rpart); rpart = fmaf(a0[5], wb.y, rpart);
        rpart = fmaf(a0[6], wb.z, rpart); rpart = fmaf(a0[7], wb.w, rpart);
        rpart += __shfl_xor(rpart, 1, 4);
        rpart += __shfl_xor(rpart, 2, 4);
        const float r = rpart + br1[idxr];

        const int wq = blockIdx.x * 64 + q;
        if (s == 0 && wq < WW) {
            float v = ((float)leaf + r) * (1.0f / 1920.0f);
            out[h * WW + wq] = (v - 0.1f) * 1.25f;
        }
    }
}

extern "C" void kernel_launch(void* const* d_in, const int* in_sizes, int n_in,
                              void* d_out, int out_size, void* d_ws, size_t ws_size,
                              hipStream_t stream) {
    const float* p[23];
    for (int i = 0; i < 23; i++) p[i] = (const float*)d_in[i];
    dim3 grid(10, HH);   // 64 pixels per block, 4 lanes per pixel
    regressor_fused<<<grid, 256, 0, stream>>>(
        p[0],
        p[1], p[2], p[3], p[4], p[5], p[6],
        p[7], p[8], p[9], p[10], p[11], p[12],
        p[13], p[14], p[15], p[16], p[17], p[18],
        p[19], p[20], p[21], p[22],
        (float*)d_out);
}

// Round 14
// 126.321 us; speedup vs baseline: 4.9489x; 1.4750x over previous
//
#include <hip/hip_runtime.h>
#include <cstddef>

#define HH 224
#define WW 608
#define HWSZ (HH * WW)

__device__ __forceinline__ float lrelu(float v) { return v > 0.0f ? v : 0.01f * v; }

// CondMul, output dim split across a 4-lane group (sub-lane s).
// Weight layout [i=0..31][o=0..CO-1] (wmat already offset by the gather index).
// Works identically for global or LDS wmat (inlined -> addrspace inferred).
// Accumulation: i ascending per output, bias last — matches reference order.
template <int CO>
__device__ __forceinline__ void cm4(const float* wmat,
                                    const float* bvec,
                                    int s, const float (&act)[8], float (&acc)[CO / 4]) {
    constexpr int CH = CO / 4;
#pragma unroll
    for (int j = 0; j < CH; j++) acc[j] = 0.0f;
#pragma unroll
    for (int sp = 0; sp < 4; sp++) {
#pragma unroll
        for (int ii = 0; ii < 8; ii++) {
            float xi = __shfl(act[ii], sp, 4);
            const float* wr = wmat + (sp * 8 + ii) * CO + s * CH;
            if constexpr (CH == 8) {
                float4 a = *reinterpret_cast<const float4*>(wr);
                float4 b = *reinterpret_cast<const float4*>(wr + 4);
                acc[0] = fmaf(xi, a.x, acc[0]); acc[1] = fmaf(xi, a.y, acc[1]);
                acc[2] = fmaf(xi, a.z, acc[2]); acc[3] = fmaf(xi, a.w, acc[3]);
                acc[4] = fmaf(xi, b.x, acc[4]); acc[5] = fmaf(xi, b.y, acc[5]);
                acc[6] = fmaf(xi, b.z, acc[6]); acc[7] = fmaf(xi, b.w, acc[7]);
            } else {
                float4 a = *reinterpret_cast<const float4*>(wr);
                acc[0] = fmaf(xi, a.x, acc[0]); acc[1] = fmaf(xi, a.y, acc[1]);
                acc[2] = fmaf(xi, a.z, acc[2]); acc[3] = fmaf(xi, a.w, acc[3]);
            }
        }
    }
#pragma unroll
    for (int j = 0; j < CH; j++) acc[j] += bvec[s * CH + j];
}

__device__ __forceinline__ void wb_lrelu8(float (&act)[8], const float (&acc)[8]) {
#pragma unroll
    for (int j = 0; j < 8; j++) act[j] = lrelu(acc[j]);
}

// First-max argmax over 16 values distributed 4-per-lane across the 4-lane group.
__device__ __forceinline__ int argmax4(const float (&v)[4], int s) {
    float bv = v[0];
    int bi = 4 * s;
#pragma unroll
    for (int j = 1; j < 4; j++) {
        if (v[j] > bv) { bv = v[j]; bi = 4 * s + j; }
    }
#pragma unroll
    for (int m = 1; m <= 2; m <<= 1) {
        float ov = __shfl_xor(bv, m, 4);
        int oi = __shfl_xor(bi, m, 4);
        if (ov > bv || (ov == bv && oi < bi)) { bv = ov; bi = oi; }
    }
    return bi;
}

// Stage NF floats (16B-aligned) into this wave's private LDS slab.
// No __syncthreads needed: slab is wave-private; per-wave DS ops are in-order
// and the compiler inserts the vmcnt/lgkmcnt waits for the load->write->read chain.
template <int NF>
__device__ __forceinline__ void stage_mat(float* ws, const float* __restrict__ src, int lane) {
    const float4* s4 = reinterpret_cast<const float4*>(src);
    float4* w4 = reinterpret_cast<float4*>(ws);
#pragma unroll
    for (int t = 0; t < NF / 4 / 64; t++) w4[t * 64 + lane] = s4[t * 64 + lane];
}

extern "C" __global__ __launch_bounds__(256, 4)
void regressor_fused(const float* __restrict__ x_in,
                     const float* __restrict__ w1_0, const float* __restrict__ b1_0,
                     const float* __restrict__ w1_1, const float* __restrict__ b1_1,
                     const float* __restrict__ w1_2, const float* __restrict__ b1_2,
                     const float* __restrict__ w2_0, const float* __restrict__ b2_0,
                     const float* __restrict__ w2_1, const float* __restrict__ b2_1,
                     const float* __restrict__ w2_2, const float* __restrict__ b2_2,
                     const float* __restrict__ w3_0, const float* __restrict__ b3_0,
                     const float* __restrict__ w3_1, const float* __restrict__ b3_1,
                     const float* __restrict__ w3_2, const float* __restrict__ b3_2,
                     const float* __restrict__ wr0, const float* __restrict__ br0,
                     const float* __restrict__ wr1, const float* __restrict__ br1,
                     float* __restrict__ out) {
    const int h = blockIdx.y;
    const int tid = threadIdx.x;
    const int p = tid >> 2;          // pixel within block (0..63)
    const int s = tid & 3;           // output-chunk sub-lane (0..3)
    const int lane = tid & 63;
    const int w = blockIdx.x * 64 + p;
    const bool valid = (w < WW);
    const int wc = valid ? w : (WW - 1);   // tail lanes compute a duplicate pixel
    const int base = h * WW + wc;

    // ---- stage-1 per-line weights (block-shared, transposed to [i][o]) ----
    __shared__ __align__(16) float sW0[1024];
    __shared__ __align__(16) float sW1[1024];
    __shared__ __align__(16) float sW2[512];
    // ---- wave-private staging slabs for uniform-class CondMuls ----
    __shared__ __align__(16) float sUni[4][1024];
    float* ws = sUni[tid >> 6];

    for (int tt = tid; tt < 1024; tt += 256) {
        int i = tt >> 5, o = tt & 31;
        sW0[tt] = w1_0[h * 1024 + o * 32 + i];
        sW1[tt] = w1_1[h * 1024 + o * 32 + i];
    }
    for (int tt = tid; tt < 512; tt += 256) {
        int i = tt >> 4, o = tt & 15;
        sW2[tt] = w1_2[h * 512 + o * 32 + i];
    }
    __syncthreads();

    float act[8], acc8[8], acc4[4];

    // ---------------- stage 1: per-line MLP -> class1 ----------------
#pragma unroll
    for (int ii = 0; ii < 8; ii++) act[ii] = x_in[(8 * s + ii) * HWSZ + base];
    cm4<32>(sW0, b1_0 + h * 32, s, act, acc8);
    wb_lrelu8(act, acc8);
    cm4<32>(sW1, b1_1 + h * 32, s, act, acc8);
    wb_lrelu8(act, acc8);
    cm4<16>(sW2, b1_2 + h * 16, s, act, acc4);
    const int i1 = argmax4(acc4, s);

    // ---------------- stage 2: CondMul on (line, class1) ----------------
#pragma unroll
    for (int ii = 0; ii < 8; ii++) act[ii] = x_in[(32 + 8 * s + ii) * HWSZ + base];
    {
        const int fi1 = __builtin_amdgcn_readfirstlane(i1);
        if (__all(i1 == fi1)) {
            // whole wave same class: stage each 4KB matrix once, read via LDS broadcast
            const size_t u = (size_t)h * 16 + (size_t)fi1;
            stage_mat<1024>(ws, w2_0 + u * 1024, lane);
            cm4<32>(ws, b2_0 + u * 32, s, act, acc8);
            wb_lrelu8(act, acc8);
            stage_mat<1024>(ws, w2_1 + u * 1024, lane);
            cm4<32>(ws, b2_1 + u * 32, s, act, acc8);
            wb_lrelu8(act, acc8);
            stage_mat<512>(ws, w2_2 + u * 512, lane);
            cm4<16>(ws, b2_2 + u * 16, s, act, acc4);
        } else {
            const size_t idx2 = (size_t)h * 16 + (size_t)i1;
            cm4<32>(w2_0 + idx2 * 1024, b2_0 + idx2 * 32, s, act, acc8);
            wb_lrelu8(act, acc8);
            cm4<32>(w2_1 + idx2 * 1024, b2_1 + idx2 * 32, s, act, acc8);
            wb_lrelu8(act, acc8);
            cm4<16>(w2_2 + idx2 * 512, b2_2 + idx2 * 16, s, act, acc4);
        }
    }
    const int i2 = argmax4(acc4, s);

    const int inds12 = i1 * 12 + (i2 - 2);               // unclipped (used below)
    const int c12 = min(max(inds12, 0), 191);

    // ---------------- stage 3: CondMul on (line, class12) ----------------
#pragma unroll
    for (int ii = 0; ii < 8; ii++) act[ii] = x_in[(64 + 8 * s + ii) * HWSZ + base];
    {
        const int fc12 = __builtin_amdgcn_readfirstlane(c12);
        if (__all(c12 == fc12)) {
            const size_t u = (size_t)h * 192 + (size_t)fc12;
            stage_mat<1024>(ws, w3_0 + u * 1024, lane);
            cm4<32>(ws, b3_0 + u * 32, s, act, acc8);
            wb_lrelu8(act, acc8);
            stage_mat<1024>(ws, w3_1 + u * 1024, lane);
            cm4<32>(ws, b3_1 + u * 32, s, act, acc8);
            wb_lrelu8(act, acc8);
            stage_mat<512>(ws, w3_2 + u * 512, lane);
            cm4<16>(ws, b3_2 + u * 16, s, act, acc4);
        } else {
            const size_t idx3 = (size_t)h * 192 + (size_t)c12;
            cm4<32>(w3_0 + idx3 * 1024, b3_0 + idx3 * 32, s, act, acc8);
            wb_lrelu8(act, acc8);
            cm4<32>(w3_1 + idx3 * 1024, b3_1 + idx3 * 32, s, act, acc8);
            wb_lrelu8(act, acc8);
            cm4<16>(w3_2 + idx3 * 512, b3_2 + idx3 * 16, s, act, acc4);
        }
    }
    const int i3 = argmax4(acc4, s);

    const int inds123 = min(max(inds12 * 10 + (i3 - 3), 0), 1919);

    // ---------------- regressor at predicted leaf ----------------
#pragma unroll
    for (int ii = 0; ii < 8; ii++) act[ii] = x_in[(96 + 8 * s + ii) * HWSZ + base];
    {
        const int sup = inds123 / 5;
        const int fsup = __builtin_amdgcn_readfirstlane(sup);
        if (__all(sup == fsup)) {
            const size_t u = (size_t)h * 384 + (size_t)fsup;
            stage_mat<1024>(ws, wr0 + u * 1024, lane);
            cm4<32>(ws, br0 + u * 32, s, act, acc8);
        } else {
            const size_t idxs = (size_t)h * 384 + (size_t)sup;
            cm4<32>(wr0 + idxs * 1024, br0 + idxs * 32, s, act, acc8);
        }
    }
    wb_lrelu8(act, acc8);

    const size_t idxr = (size_t)h * 1920 + (size_t)inds123;
    const float* __restrict__ wr1r = wr1 + idxr * 32 + 8 * s;
    float4 wa = *reinterpret_cast<const float4*>(wr1r);
    float4 wb = *reinterpret_cast<const float4*>(wr1r + 4);
    float rpart = 0.0f;
    rpart = fmaf(act[0], wa.x, rpart); rpart = fmaf(act[1], wa.y, rpart);
    rpart = fmaf(act[2], wa.z, rpart); rpart = fmaf(act[3], wa.w, rpart);
    rpart = fmaf(act[4], wb.x, rpart); rpart = fmaf(act[5], wb.y, rpart);
    rpart = fmaf(act[6], wb.z, rpart); rpart = fmaf(act[7], wb.w, rpart);
    rpart += __shfl_xor(rpart, 1, 4);
    rpart += __shfl_xor(rpart, 2, 4);
    const float r = rpart + br1[idxr];

    if (s == 0 && valid) {
        float v = ((float)inds123 + r) * (1.0f / 1920.0f);
        out[h * WW + w] = (v - 0.1f) * 1.25f;
    }
}

extern "C" void kernel_launch(void* const* d_in, const int* in_sizes, int n_in,
                              void* d_out, int out_size, void* d_ws, size_t ws_size,
                              hipStream_t stream) {
    const float* p[23];
    for (int i = 0; i < 23; i++) p[i] = (const float*)d_in[i];
    dim3 grid(10, HH);   // 64 pixels per block, 4 lanes per pixel
    regressor_fused<<<grid, 256, 0, stream>>>(
        p[0],
        p[1], p[2], p[3], p[4], p[5], p[6],
        p[7], p[8], p[9], p[10], p[11], p[12],
        p[13], p[14], p[15], p[16], p[17], p[18],
        p[19], p[20], p[21], p[22],
        (float*)d_out);
}